// Round 3
// baseline (795.884 us; speedup 1.0000x reference)
//
#include <hip/hip_runtime.h>
#include <math.h>

// dims
#define Bv 2
#define Cv 64
#define Hv 512
#define Wv 512
#define Tv 16
#define Kv 1024
#define KMAXv 256
#define HIDv 128
#define HWv (Hv * Wv) // 262144
#define DCH 16        // hid chunk size

// output flat offsets (f32 elements)
#define OFF_HEAVY 0
#define OFF_DETAIL 33554432
#define OFF_ALPHA 67108864
#define OFF_PROB 67633152
#define OFF_GATES 67635200
#define OFF_EC 67637248
#define OFF_BL 67637249

// ws layout (bytes): selflag int[2048] @0 ; cost float[2] @8192
#define WS_SEL_OFF 0
#define WS_COST_OFF 8192

typedef float f4 __attribute__((ext_vector_type(4)));

// ---------------- selection + probabilities/gates + cost partials ----------------
__global__ __launch_bounds__(1024) void sel_kernel(const float* __restrict__ u,
                                                   float* __restrict__ out,
                                                   int* __restrict__ selflag,
                                                   float* __restrict__ costp) {
    int b = blockIdx.x;
    int t = threadIdx.x;
    __shared__ float us[Kv];
    __shared__ float red[16];

    float ui = u[b * Kv + t];
    us[t] = ui;
    __syncthreads();

    float p = 1.0f / (1.0f + __expf(-ui));
    float hard = (ui >= 0.0f) ? 1.0f : 0.0f;
    out[OFF_PROB + b * Kv + t] = p;
    out[OFF_GATES + b * Kv + t] = (hard + p) - p; // STE forward

    float cost = p + (1.0f - p) * 0.1f;
    #pragma unroll
    for (int o = 32; o > 0; o >>= 1) cost += __shfl_down(cost, o, 64);
    int wave = t >> 6, lane = t & 63;
    if (lane == 0) red[wave] = cost;
    __syncthreads();
    if (t == 0) {
        float s = 0.f;
        #pragma unroll
        for (int i = 0; i < 16; i++) s += red[i];
        costp[b] = s;
    }

    // rank among masked values
    int selected = 0;
    if (ui >= 0.0f) {
        int r = 0;
        for (int j = 0; j < Kv; j += 4) {
            float4 uj = *(const float4*)&us[j];
            r += (uj.x > ui) || (uj.x == ui && (j + 0) < t);
            r += (uj.y > ui) || (uj.y == ui && (j + 1) < t);
            r += (uj.z > ui) || (uj.z == ui && (j + 2) < t);
            r += (uj.w > ui) || (uj.w == ui && (j + 3) < t);
        }
        selected = (r < KMAXv) ? 1 : 0;
    }
    selflag[b * Kv + t] = selected;
}

// ---------------- copy kernel: unselected tiles only, low-VGPR, BW-bound ----------------
__global__ __launch_bounds__(256) void copy_kernel(const float* __restrict__ x,
                                                   float* __restrict__ out,
                                                   const int* __restrict__ selflag,
                                                   const float* __restrict__ costp) {
    int blk = blockIdx.x;
    int t = threadIdx.x;

    if (blk == 0 && t == 0) {
        float ec = costp[0] + costp[1];
        out[OFF_EC] = ec;
        out[OFF_BL] = (ec > 1024.0f) ? (ec - 1024.0f) : 0.0f;
    }

    if (selflag[blk]) return;

    int b = blk >> 10;
    int tile = blk & 1023;
    int gh = tile >> 5, gw = tile & 31;
    int h0 = gh * Tv, w0 = gw * Tv;

    int cplane = t >> 6;         // 0..3
    int r = (t >> 2) & 15;       // row in tile
    int q = t & 3;               // float4 within row
    int base = ((b * Cv + cplane) * Hv + (h0 + r)) * Wv + w0 + q * 4;
    float4 z = make_float4(0.f, 0.f, 0.f, 0.f);
    #pragma unroll 4
    for (int c4 = 0; c4 < 16; c4++) {
        int idx = base + c4 * 4 * HWv;
        float4 v = *(const float4*)&x[idx];
        *(float4*)&out[OFF_HEAVY + idx] = v;
        *(float4*)&out[OFF_DETAIL + idx] = z;
    }
    if (t < 64) {
        int r2 = t >> 2, q2 = t & 3;
        int aidx = (b * Hv + h0 + r2) * Wv + w0 + q2 * 4;
        *(float4*)&out[OFF_ALPHA + aidx] = z;
    }
}

// ---------------- mlp kernel ----------------
// Round-3 lever: weight loads global->LDS. The 4096 wave-uniform 16B global
// loads per thread (~200cy L2-hit each, near-serialized at ArchVGPR=88) were
// the stall: VALUBusy 14%, HBM 4.6%, 10x over the 27us FMA floor. Weights now
// staged per-16-hid chunk into LDS (8KB) and read as ds_read_b128 broadcasts
// (~70cy, pipelined via compiler lgkmcnt). LDS total 72KB -> 2 blocks/CU kept.

#define GELU1(ZV) { float zv_ = (ZV); \
    float zz_ = 0.7978845608028654f * (zv_ + 0.044715f * zv_ * zv_ * zv_); \
    float e_ = __expf(2.0f * zz_); \
    float th_ = 1.0f - 2.0f / (e_ + 1.0f); \
    (ZV) = 0.5f * zv_ * (1.0f + th_); }
#define GELU4(V) GELU1(V.x) GELU1(V.y) GELU1(V.z) GELU1(V.w)

// layer-2 scalar step: D += hj * w2row (from LDS), advance row pointer
#define L2S(HJ) { float hj_ = (HJ); \
    D0  += hj_ * w2p[0];  D1  += hj_ * w2p[1];  D2  += hj_ * w2p[2];  D3  += hj_ * w2p[3]; \
    D4  += hj_ * w2p[4];  D5  += hj_ * w2p[5];  D6  += hj_ * w2p[6];  D7  += hj_ * w2p[7]; \
    D8  += hj_ * w2p[8];  D9  += hj_ * w2p[9];  D10 += hj_ * w2p[10]; D11 += hj_ * w2p[11]; \
    D12 += hj_ * w2p[12]; D13 += hj_ * w2p[13]; D14 += hj_ * w2p[14]; D15 += hj_ * w2p[15]; \
    w2p += 16; }
#define L2V(HV) L2S(HV.x) L2S(HV.y) L2S(HV.z) L2S(HV.w)

// epilogue per channel
#define EPI1(DC, C) { float det_ = (DC); int idx_ = pbase + (C) * HWv; \
    out[OFF_DETAIL + idx_] = det_; \
    out[OFF_HEAVY + idx_] = xs[C][t] + alpha * det_; }
#define EPI4(DV, C0) EPI1(DV.x, (C0)) EPI1(DV.y, (C0)+1) EPI1(DV.z, (C0)+2) EPI1(DV.w, (C0)+3)

__global__ __launch_bounds__(256, 2) void mlp_kernel(const float* __restrict__ x,
                                                     const float* __restrict__ W1,
                                                     const float* __restrict__ b1,
                                                     const float* __restrict__ W2,
                                                     const float* __restrict__ b2,
                                                     const float* __restrict__ Wa,
                                                     const float* __restrict__ ba,
                                                     float* __restrict__ out,
                                                     const int* __restrict__ selflag) {
    int blk = blockIdx.x;
    if (!selflag[blk]) return;

    __shared__ float xs[Cv][256];     // 64KB: xs[c][pixel]
    __shared__ float w1c[Cv][DCH];    // 4KB:  W1[:, d0:d0+16] chunk
    __shared__ float w2c[DCH][Cv];    // 4KB:  W2[d0:d0+16, :] chunk

    int t = threadIdx.x;
    int b = blk >> 10;
    int tile = blk & 1023;
    int gh = tile >> 5, gw = tile & 31;
    int h0 = gh * Tv, w0 = gw * Tv;

    int pr = t >> 4, pc = t & 15;
    int pbase = ((b * Cv) * Hv + (h0 + pr)) * Wv + w0 + pc; // channel-0 addr of my pixel

    // stage x tile into LDS: xs[c][pixel]
    #pragma unroll 8
    for (int c = 0; c < Cv; c++) xs[c][t] = x[pbase + c * HWv];
    __syncthreads();

    // alpha = sigmoid(x . Wa + ba)
    float aacc = ba[0];
    #pragma unroll 8
    for (int c = 0; c < Cv; c++) aacc += xs[c][t] * Wa[c];
    float alpha = 1.0f / (1.0f + __expf(-aacc));
    out[OFF_ALPHA + (b * Hv + h0 + pr) * Wv + w0 + pc] = alpha;

    // detail accumulators in named registers, init to b2
    f4 D0  = *(const f4*)&b2[0],  D1  = *(const f4*)&b2[4],  D2  = *(const f4*)&b2[8],  D3  = *(const f4*)&b2[12];
    f4 D4  = *(const f4*)&b2[16], D5  = *(const f4*)&b2[20], D6  = *(const f4*)&b2[24], D7  = *(const f4*)&b2[28];
    f4 D8  = *(const f4*)&b2[32], D9  = *(const f4*)&b2[36], D10 = *(const f4*)&b2[40], D11 = *(const f4*)&b2[44];
    f4 D12 = *(const f4*)&b2[48], D13 = *(const f4*)&b2[52], D14 = *(const f4*)&b2[56], D15 = *(const f4*)&b2[60];

    // weight-staging decomposition for this thread (one f4 of w1c, one of w2c)
    int sc = t >> 2, sq = t & 3;  // w1c: channel sc, f4 sq (DCH=16 floats/row)

    // hid-chunked two-layer MLP (8 chunks of 16 hid), weights LDS-staged per chunk
    #pragma unroll 1
    for (int d0 = 0; d0 < HIDv; d0 += DCH) {
        __syncthreads(); // previous chunk's reads complete before overwrite
        *(f4*)&w1c[sc][sq * 4] = *(const f4*)(W1 + sc * HIDv + d0 + sq * 4);
        ((f4*)w2c)[t] = *(const f4*)(W2 + d0 * Cv + t * 4);
        __syncthreads(); // chunk published

        f4 H0 = *(const f4*)&b1[d0 + 0], H1 = *(const f4*)&b1[d0 + 4];
        f4 H2 = *(const f4*)&b1[d0 + 8], H3 = *(const f4*)&b1[d0 + 12];

        // layer 1: H += x_c * w1c[c][:]  (wave-uniform LDS broadcast reads)
        #pragma unroll 4
        for (int c = 0; c < Cv; c++) {
            float xc = xs[c][t];
            const f4* wp = (const f4*)&w1c[c][0];
            H0 += xc * wp[0]; H1 += xc * wp[1]; H2 += xc * wp[2]; H3 += xc * wp[3];
        }

        // gelu (tanh approx, matches jax.nn.gelu)
        GELU4(H0) GELU4(H1) GELU4(H2) GELU4(H3)

        // layer 2: D += H_j * w2c[j][:]  (16 rows, macro-unrolled, LDS broadcast)
        const f4* w2p = (const f4*)w2c;
        L2V(H0) L2V(H1) L2V(H2) L2V(H3)
    }

    // epilogue: detail_out, heavy
    EPI4(D0, 0)   EPI4(D1, 4)   EPI4(D2, 8)   EPI4(D3, 12)
    EPI4(D4, 16)  EPI4(D5, 20)  EPI4(D6, 24)  EPI4(D7, 28)
    EPI4(D8, 32)  EPI4(D9, 36)  EPI4(D10, 40) EPI4(D11, 44)
    EPI4(D12, 48) EPI4(D13, 52) EPI4(D14, 56) EPI4(D15, 60)
}

extern "C" void kernel_launch(void* const* d_in, const int* in_sizes, int n_in,
                              void* d_out, int out_size, void* d_ws, size_t ws_size,
                              hipStream_t stream) {
    const float* x  = (const float*)d_in[0];
    const float* u  = (const float*)d_in[1];
    const float* W1 = (const float*)d_in[2];
    const float* b1 = (const float*)d_in[3];
    const float* W2 = (const float*)d_in[4];
    const float* b2 = (const float*)d_in[5];
    const float* Wa = (const float*)d_in[6];
    const float* ba = (const float*)d_in[7];
    float* out = (float*)d_out;

    char* ws = (char*)d_ws;
    int*   selflag = (int*)(ws + WS_SEL_OFF);
    float* costp   = (float*)(ws + WS_COST_OFF);

    sel_kernel<<<Bv, 1024, 0, stream>>>(u, out, selflag, costp);
    copy_kernel<<<Bv * Kv, 256, 0, stream>>>(x, out, selflag, costp);
    mlp_kernel<<<Bv * Kv, 256, 0, stream>>>(x, W1, b1, W2, b2, Wa, ba, out, selflag);
}

// Round 4
// 587.560 us; speedup vs baseline: 1.3546x; 1.3546x over previous
//
#include <hip/hip_runtime.h>
#include <math.h>

// dims
#define Bv 2
#define Cv 64
#define Hv 512
#define Wv 512
#define Tv 16
#define Kv 1024
#define KMAXv 256
#define HIDv 128
#define HWv (Hv * Wv) // 262144

// output flat offsets (f32 elements)
#define OFF_HEAVY 0
#define OFF_DETAIL 33554432
#define OFF_ALPHA 67108864
#define OFF_PROB 67633152
#define OFF_GATES 67635200
#define OFF_EC 67637248
#define OFF_BL 67637249

// ws layout (bytes): selflag int[2048] @0 ; cost float[2] @8192 ;
// list int[512] @8256 ; selcnt int[2] @10304
#define WS_SEL_OFF 0
#define WS_COST_OFF 8192
#define WS_LIST_OFF 8256
#define WS_CNT_OFF 10304

typedef float f4 __attribute__((ext_vector_type(4)));
#define SPLAT(s) ((f4){(s), (s), (s), (s)})

// ---------------- selection + probabilities/gates + cost + compact list ----------------
__global__ __launch_bounds__(1024) void sel_kernel(const float* __restrict__ u,
                                                   float* __restrict__ out,
                                                   int* __restrict__ selflag,
                                                   float* __restrict__ costp,
                                                   int* __restrict__ list,
                                                   int* __restrict__ selcnt) {
    int b = blockIdx.x;
    int t = threadIdx.x;
    __shared__ float us[Kv];
    __shared__ float red[16];
    __shared__ int redc[16];

    float ui = u[b * Kv + t];
    us[t] = ui;
    __syncthreads();

    float p = 1.0f / (1.0f + __expf(-ui));
    float hard = (ui >= 0.0f) ? 1.0f : 0.0f;
    out[OFF_PROB + b * Kv + t] = p;
    out[OFF_GATES + b * Kv + t] = (hard + p) - p; // STE forward

    float cost = p + (1.0f - p) * 0.1f;
    #pragma unroll
    for (int o = 32; o > 0; o >>= 1) cost += __shfl_down(cost, o, 64);
    int wave = t >> 6, lane = t & 63;
    if (lane == 0) red[wave] = cost;

    // rank among masked values (total order: value desc, index asc)
    int selected = 0;
    int r = 0;
    if (ui >= 0.0f) {
        for (int j = 0; j < Kv; j += 4) {
            float4 uj = *(const float4*)&us[j];
            r += (uj.x > ui) || (uj.x == ui && (j + 0) < t);
            r += (uj.y > ui) || (uj.y == ui && (j + 1) < t);
            r += (uj.z > ui) || (uj.z == ui && (j + 2) < t);
            r += (uj.w > ui) || (uj.w == ui && (j + 3) < t);
        }
        selected = (r < KMAXv) ? 1 : 0;
    }
    selflag[b * Kv + t] = selected;
    if (selected) list[b * KMAXv + r] = t;  // rank is dense {0..cnt-1} -> compact slot

    unsigned long long m = __ballot(selected != 0);
    if (lane == 0) redc[wave] = (int)__popcll(m);
    __syncthreads();
    if (t == 0) {
        float s = 0.f;
        int sc = 0;
        #pragma unroll
        for (int i = 0; i < 16; i++) { s += red[i]; sc += redc[i]; }
        costp[b] = s;
        selcnt[b] = sc;
    }
}

// ---------------- copy kernel: unselected tiles only, BW-bound ----------------
__global__ __launch_bounds__(256) void copy_kernel(const float* __restrict__ x,
                                                   float* __restrict__ out,
                                                   const int* __restrict__ selflag,
                                                   const float* __restrict__ costp) {
    int blk = blockIdx.x;
    int t = threadIdx.x;

    if (blk == 0 && t == 0) {
        float ec = costp[0] + costp[1];
        out[OFF_EC] = ec;
        out[OFF_BL] = (ec > 1024.0f) ? (ec - 1024.0f) : 0.0f;
    }

    if (selflag[blk]) return;

    int b = blk >> 10;
    int tile = blk & 1023;
    int gh = tile >> 5, gw = tile & 31;
    int h0 = gh * Tv, w0 = gw * Tv;

    int cplane = t >> 6;         // 0..3
    int r = (t >> 2) & 15;       // row in tile
    int q = t & 3;               // float4 within row
    int base = ((b * Cv + cplane) * Hv + (h0 + r)) * Wv + w0 + q * 4;
    float4 z = make_float4(0.f, 0.f, 0.f, 0.f);
    #pragma unroll 4
    for (int c4 = 0; c4 < 16; c4++) {
        int idx = base + c4 * 4 * HWv;
        float4 v = *(const float4*)&x[idx];
        *(float4*)&out[OFF_HEAVY + idx] = v;
        *(float4*)&out[OFF_DETAIL + idx] = z;
    }
    if (t < 64) {
        int r2 = t >> 2, q2 = t & 3;
        int aidx = (b * Hv + h0 + r2) * Wv + w0 + q2 * 4;
        *(float4*)&out[OFF_ALPHA + aidx] = z;
    }
}

// ---------------- mlp kernel: register-tiled two-stage GEMM ----------------
// Each thread owns an 8px x 8ch output tile (D, 16 named f4) and per 64-hid
// chunk an 8px x 8hid H tile (16 named f4). Per K-step: 2 weight f4 + 2
// activation f4 loads feed 64 FMAs -> load:compute 1:8 (was 1:1 at R=1,
// which capped VALUBusy at ~15% across 3 rounds regardless of weight path).
// H redistributed via 64KB LDS per chunk; x/H in pixel-interleaved LDS
// layout (pp = oct*4 + half*128 + i) so all LDS ops are <=2-way = free.
// Weights read global wave-uniform (broadcast, L1/L2-hit, hidden under FMA).
// Grid = 512 compacted blocks (sel's rank = dense slot) for load balance.

#define GELU1(ZV) { float zv_ = (ZV); \
    float zz_ = 0.7978845608028654f * (zv_ + 0.044715f * zv_ * zv_ * zv_); \
    float e_ = __expf(2.0f * zz_); \
    float th_ = 1.0f - 2.0f / (e_ + 1.0f); \
    (ZV) = 0.5f * zv_ * (1.0f + th_); }
#define GELU4(V) GELU1(V.x) GELU1(V.y) GELU1(V.z) GELU1(V.w)

#define EPI(K, DK0, DK1) { \
    int a_ = abase + (K) * HWv; \
    f4 xv0_ = *(const f4*)&xs[cg * 8 + (K)][o4]; \
    f4 xv1_ = *(const f4*)&xs[cg * 8 + (K)][o4 + 128]; \
    *(f4*)&out[OFF_DETAIL + a_]     = DK0; \
    *(f4*)&out[OFF_DETAIL + a_ + 4] = DK1; \
    *(f4*)&out[OFF_HEAVY + a_]      = xv0_ + av0 * DK0; \
    *(f4*)&out[OFF_HEAVY + a_ + 4]  = xv1_ + av1 * DK1; }

__global__ __launch_bounds__(256, 1) void mlp_kernel(const float* __restrict__ x,
                                                     const float* __restrict__ W1,
                                                     const float* __restrict__ b1,
                                                     const float* __restrict__ W2,
                                                     const float* __restrict__ b2,
                                                     const float* __restrict__ Wa,
                                                     const float* __restrict__ ba,
                                                     float* __restrict__ out,
                                                     const int* __restrict__ list,
                                                     const int* __restrict__ selcnt) {
    int g = blockIdx.x;
    int b = g >> 8, s = g & 255;
    if (s >= selcnt[b]) return;           // uniform per block
    int tile = list[b * KMAXv + s];

    __shared__ float xs[Cv][256];  // 64KB, pixel-interleaved columns
    __shared__ float Hs[64][256];  // 64KB, one 64-hid chunk, same layout
    __shared__ float als[256];     // alpha per pixel (interleaved)

    int t = threadIdx.x;
    int gh = tile >> 5, gw = tile & 31;
    int h0 = gh * Tv, w0 = gw * Tv;

    // --- pixel-per-thread role: staging + alpha (pixel p = t) ---
    int pp = ((t >> 3) << 2) + (((t >> 2) & 1) << 7) + (t & 3); // interleaved col
    int pbase = ((b * Cv) * Hv + (h0 + (t >> 4))) * Wv + w0 + (t & 15);
    #pragma unroll 8
    for (int c = 0; c < Cv; c++) xs[c][pp] = x[pbase + c * HWv];
    __syncthreads();

    float aacc = ba[0];
    #pragma unroll 8
    for (int c = 0; c < Cv; c++) aacc += xs[c][pp] * Wa[c];
    float alpha = 1.0f / (1.0f + __expf(-aacc));
    out[OFF_ALPHA + (b * Hv + h0 + (t >> 4)) * Wv + w0 + (t & 15)] = alpha;
    als[pp] = alpha;

    // --- GEMM roles: oct o (8 px), channel/hid group cg (8 wide) ---
    int o = t & 31, cg = t >> 5;
    int o4 = o * 4;

    f4 b2a = *(const f4*)&b2[cg * 8], b2b = *(const f4*)&b2[cg * 8 + 4];
    f4 D00 = SPLAT(b2a.x), D01 = SPLAT(b2a.x), D10 = SPLAT(b2a.y), D11 = SPLAT(b2a.y),
       D20 = SPLAT(b2a.z), D21 = SPLAT(b2a.z), D30 = SPLAT(b2a.w), D31 = SPLAT(b2a.w),
       D40 = SPLAT(b2b.x), D41 = SPLAT(b2b.x), D50 = SPLAT(b2b.y), D51 = SPLAT(b2b.y),
       D60 = SPLAT(b2b.z), D61 = SPLAT(b2b.z), D70 = SPLAT(b2b.w), D71 = SPLAT(b2b.w);

    #pragma unroll 1
    for (int q = 0; q < 2; q++) {
        f4 b1a = *(const f4*)&b1[q * 64 + cg * 8];
        f4 b1b = *(const f4*)&b1[q * 64 + cg * 8 + 4];
        f4 H00 = SPLAT(b1a.x), H01 = SPLAT(b1a.x), H10 = SPLAT(b1a.y), H11 = SPLAT(b1a.y),
           H20 = SPLAT(b1a.z), H21 = SPLAT(b1a.z), H30 = SPLAT(b1a.w), H31 = SPLAT(b1a.w),
           H40 = SPLAT(b1b.x), H41 = SPLAT(b1b.x), H50 = SPLAT(b1b.y), H51 = SPLAT(b1b.y),
           H60 = SPLAT(b1b.z), H61 = SPLAT(b1b.z), H70 = SPLAT(b1b.w), H71 = SPLAT(b1b.w);

        // GEMM-1: H[8px][8hid] += x[c][8px] (LDS) * W1[c][8hid] (global broadcast)
        const float* w1p = W1 + q * 64 + cg * 8;
        #pragma unroll 4
        for (int c = 0; c < Cv; c++) {
            f4 wa  = *(const f4*)(w1p + c * HIDv);
            f4 wb  = *(const f4*)(w1p + c * HIDv + 4);
            f4 xv0 = *(const f4*)&xs[c][o4];
            f4 xv1 = *(const f4*)&xs[c][o4 + 128];
            H00 += wa.x * xv0; H01 += wa.x * xv1; H10 += wa.y * xv0; H11 += wa.y * xv1;
            H20 += wa.z * xv0; H21 += wa.z * xv1; H30 += wa.w * xv0; H31 += wa.w * xv1;
            H40 += wb.x * xv0; H41 += wb.x * xv1; H50 += wb.y * xv0; H51 += wb.y * xv1;
            H60 += wb.z * xv0; H61 += wb.z * xv1; H70 += wb.w * xv0; H71 += wb.w * xv1;
        }

        GELU4(H00) GELU4(H01) GELU4(H10) GELU4(H11)
        GELU4(H20) GELU4(H21) GELU4(H30) GELU4(H31)
        GELU4(H40) GELU4(H41) GELU4(H50) GELU4(H51)
        GELU4(H60) GELU4(H61) GELU4(H70) GELU4(H71)

        __syncthreads(); // prev chunk's GEMM-2 done reading Hs
        int hr = cg * 8;
        *(f4*)&Hs[hr + 0][o4] = H00; *(f4*)&Hs[hr + 0][o4 + 128] = H01;
        *(f4*)&Hs[hr + 1][o4] = H10; *(f4*)&Hs[hr + 1][o4 + 128] = H11;
        *(f4*)&Hs[hr + 2][o4] = H20; *(f4*)&Hs[hr + 2][o4 + 128] = H21;
        *(f4*)&Hs[hr + 3][o4] = H30; *(f4*)&Hs[hr + 3][o4 + 128] = H31;
        *(f4*)&Hs[hr + 4][o4] = H40; *(f4*)&Hs[hr + 4][o4 + 128] = H41;
        *(f4*)&Hs[hr + 5][o4] = H50; *(f4*)&Hs[hr + 5][o4 + 128] = H51;
        *(f4*)&Hs[hr + 6][o4] = H60; *(f4*)&Hs[hr + 6][o4 + 128] = H61;
        *(f4*)&Hs[hr + 7][o4] = H70; *(f4*)&Hs[hr + 7][o4 + 128] = H71;
        __syncthreads(); // Hs published

        // GEMM-2: D[8px][8ch] += H[j][8px] (LDS) * W2[j][8ch] (global broadcast)
        const float* w2p = W2 + (q * 64) * Cv + cg * 8;
        #pragma unroll 4
        for (int j = 0; j < 64; j++) {
            f4 wa  = *(const f4*)(w2p + j * Cv);
            f4 wb  = *(const f4*)(w2p + j * Cv + 4);
            f4 hv0 = *(const f4*)&Hs[j][o4];
            f4 hv1 = *(const f4*)&Hs[j][o4 + 128];
            D00 += wa.x * hv0; D01 += wa.x * hv1; D10 += wa.y * hv0; D11 += wa.y * hv1;
            D20 += wa.z * hv0; D21 += wa.z * hv1; D30 += wa.w * hv0; D31 += wa.w * hv1;
            D40 += wb.x * hv0; D41 += wb.x * hv1; D50 += wb.y * hv0; D51 += wb.y * hv1;
            D60 += wb.z * hv0; D61 += wb.z * hv1; D70 += wb.w * hv0; D71 += wb.w * hv1;
        }
    }

    // --- epilogue: detail_out, heavy for the thread's 8px x 8ch tile ---
    f4 av0 = *(const f4*)&als[o4];
    f4 av1 = *(const f4*)&als[o4 + 128];
    // pixel p0 = o*8 (h=0), p1 = o*8+4 (h=1): row o>>1, cols (o&1)*8 and +4
    int abase = ((b * Cv + cg * 8) * Hv + h0 + (o >> 1)) * Wv + w0 + (o & 1) * 8;
    EPI(0, D00, D01) EPI(1, D10, D11) EPI(2, D20, D21) EPI(3, D30, D31)
    EPI(4, D40, D41) EPI(5, D50, D51) EPI(6, D60, D61) EPI(7, D70, D71)
}

extern "C" void kernel_launch(void* const* d_in, const int* in_sizes, int n_in,
                              void* d_out, int out_size, void* d_ws, size_t ws_size,
                              hipStream_t stream) {
    const float* x  = (const float*)d_in[0];
    const float* u  = (const float*)d_in[1];
    const float* W1 = (const float*)d_in[2];
    const float* b1 = (const float*)d_in[3];
    const float* W2 = (const float*)d_in[4];
    const float* b2 = (const float*)d_in[5];
    const float* Wa = (const float*)d_in[6];
    const float* ba = (const float*)d_in[7];
    float* out = (float*)d_out;

    char* ws = (char*)d_ws;
    int*   selflag = (int*)(ws + WS_SEL_OFF);
    float* costp   = (float*)(ws + WS_COST_OFF);
    int*   list    = (int*)(ws + WS_LIST_OFF);
    int*   selcnt  = (int*)(ws + WS_CNT_OFF);

    sel_kernel<<<Bv, 1024, 0, stream>>>(u, out, selflag, costp, list, selcnt);
    copy_kernel<<<Bv * Kv, 256, 0, stream>>>(x, out, selflag, costp);
    mlp_kernel<<<Bv * KMAXv, 256, 0, stream>>>(x, W1, b1, W2, b2, Wa, ba, out, list, selcnt);
}